// Round 17
// baseline (564.023 us; speedup 1.0000x reference)
//
#include <hip/hip_runtime.h>

#define BSZ 32
#define NN 24
#define TT 12
#define FF 3
#define KK 3
#define COUT 12
#define DIN 313          // N*COUT + N + 1
#define HID 3756         // DIN*T
#define H4 15024         // 4*HID
#define KP 3776          // HID padded to 118*32
#define KPI 320          // DIN padded to 10*32
#define NTILES 470       // ceil(15024/32)
#define NB 235           // j-tiles for fused step
#define NCH 30           // K chunk-groups of 4 ks

using short8 = __attribute__((ext_vector_type(8))) short;
using f32x4  = __attribute__((ext_vector_type(4))) float;

__device__ inline unsigned short f2bf(float f){
  union{float f; unsigned u;} v; v.f=f;
  unsigned u=v.u;
  return (unsigned short)((u + 0x7FFFu + ((u>>16)&1u))>>16);
}
__device__ inline f32x4 mfma16(short8 a, short8 b, f32x4 c){
  return __builtin_amdgcn_mfma_f32_16x16x32_bf16(a,b,c,0,0,0);
}
__device__ inline float sigm(float x){ return 1.f/(1.f+expf(-x)); }

// ---------- pack W_hh chunk-groups [cg0,cg1) for slab bi (LDS transpose) ----------
__device__ void conv_slab(const float* __restrict__ W, unsigned short* __restrict__ Wp,
    int bi, int cg0, int cg1, int tid, int nthr, unsigned short* lds){
  for(int cg=cg0; cg<cg1; cg++){
    int ks0=cg*4;
    int nks=min(4,118-ks0);
    int nf4=nks*8;
    for(int q=tid;q<64*nf4;q+=nthr){
      int r=q/nf4, f4=q-r*nf4;
      int g=r>>4, lj=r&15;
      int jj=bi*16+lj; if(jj>=HID) jj=HID-1;
      const float* src=W+(long)(g*HID+jj)*HID;
      int k=ks0*32+f4*4;
      ushort4 o;
      if(k+3<HID){
        float4 v=*(const float4*)(src+k);
        o.x=f2bf(v.x); o.y=f2bf(v.y); o.z=f2bf(v.z); o.w=f2bf(v.w);
      } else {
        float vv[4];
        #pragma unroll
        for(int t2=0;t2<4;t2++){ int kk=k+t2; vv[t2]=(kk<HID)?src[kk]:0.f; }
        o.x=f2bf(vv[0]); o.y=f2bf(vv[1]); o.z=f2bf(vv[2]); o.w=f2bf(vv[3]);
      }
      *(ushort4*)(&lds[r*136+f4*4])=o;
    }
    __syncthreads();
    for(int idx=tid; idx<nks*4*64; idx+=nthr){
      int l=idx&63, g=(idx>>6)&3, kl=idx>>8;
      int lj=l&15, lk=l>>4;
      short8 v=*(short8*)(&lds[(g*16+lj)*136 + kl*32 + lk*8]);
      *(short8*)(Wp + (((long)(bi*118+ks0+kl)*4+g)*64 + l)*8) = v;
    }
    __syncthreads();
  }
}

// ---------- pack W_ih slab jt into per-wave-contiguous bf16 ----------
__device__ void pack_ih(const float* __restrict__ Wih, unsigned short* __restrict__ Wip,
    int jt, int tid, int nthr, unsigned short* lds /*32*328*/){
  int j0=jt*32;
  for(int q=tid;q<32*80;q+=nthr){
    int r=q/80, f4=q-r*80;
    int j=j0+r;
    int k=f4*4;
    ushort4 o;
    if(j<H4){
      const float* src=Wih+(long)j*DIN;
      float vv[4];
      #pragma unroll
      for(int t2=0;t2<4;t2++){ int kk=k+t2; vv[t2]=(kk<DIN)?src[kk]:0.f; }
      o.x=f2bf(vv[0]); o.y=f2bf(vv[1]); o.z=f2bf(vv[2]); o.w=f2bf(vv[3]);
    } else { o.x=0;o.y=0;o.z=0;o.w=0; }
    *(ushort4*)(&lds[r*328+k])=o;
  }
  __syncthreads();
  for(int u=tid;u<1280;u+=nthr){
    int l=u&63, jh=(u>>6)&1, ks=u>>7;
    int lj=l&15, lk=l>>4;
    short8 v=*(short8*)(&lds[(jh*16+lj)*328 + ks*32 + lk*8]);
    *(short8*)(Wip + (((long)(jt*10+ks)*2+jh)*512) + l*8)=v;
  }
  __syncthreads();
}

// ---------- F1: attn (0..31) + conv cg[0,8) (32..266) + packih (267..384) ----------
__global__ void __launch_bounds__(256) k_f1(const float* __restrict__ X,
   const float* __restrict__ sa_W1, const float* __restrict__ sa_W2,
   const float* __restrict__ sa_W3, const float* __restrict__ sa_bs,
   const float* __restrict__ sa_Vs, const float* __restrict__ ta_U1,
   const float* __restrict__ ta_U2, const float* __restrict__ ta_U3,
   const float* __restrict__ ta_be, const float* __restrict__ ta_Ve,
   float* __restrict__ SA_pre, float* __restrict__ TA_pre,
   const float* __restrict__ W, unsigned short* __restrict__ Wp,
   const float* __restrict__ Wih, unsigned short* __restrict__ Wip){
  __shared__ __align__(16) float smf[5248];
  int tid=threadIdx.x;
  if(blockIdx.x>=267){
    int cb=blockIdx.x-267;
    #pragma unroll
    for(int s=0;s<4;s++){
      int jt=cb*4+s;
      if(jt<NTILES) pack_ih(Wih,Wip,jt,tid,256,(unsigned short*)smf);
    }
    return;
  }
  if(blockIdx.x>=32){
    conv_slab(W,Wp,blockIdx.x-32,0,8,tid,256,(unsigned short*)smf);
    return;
  }
  int b=blockIdx.x;
  float* lin=smf;        float* lhs=smf+864;   float* rhs=smf+1152;
  float* P=smf+1440;     float* S=smf+2016;    float* lhsT=smf+2592;
  float* rhsT=smf+2880;  float* PT=smf+3168;   float* E=smf+3312;
  for(int i=tid;i<864;i+=256) lin[i]=X[b*864+i];
  __syncthreads();
  for(int i=tid;i<NN*TT;i+=256){ int n=i/TT, t=i%TT;
    float acc=0;
    #pragma unroll
    for(int f=0;f<FF;f++){
      float t1=0;
      for(int u=0;u<TT;u++) t1 += lin[n*36+u*3+f]*sa_W1[u];
      acc += t1*sa_W2[f*TT+t];
    }
    lhs[n*TT+t]=acc;
    float r=0;
    #pragma unroll
    for(int f=0;f<FF;f++) r += sa_W3[f]*lin[n*36+t*3+f];
    rhs[t*NN+n]=r;
  }
  for(int i=tid;i<TT*NN;i+=256){ int t=i/NN, n=i%NN;
    float acc=0;
    #pragma unroll
    for(int f=0;f<FF;f++){
      float t1=0;
      for(int m=0;m<NN;m++) t1 += lin[m*36+t*3+f]*ta_U1[m];
      acc += t1*ta_U2[f*NN+n];
    }
    lhsT[t*NN+n]=acc;
    float r=0;
    #pragma unroll
    for(int f=0;f<FF;f++) r += ta_U3[f]*lin[n*36+t*3+f];
    rhsT[n*TT+t]=r;
  }
  __syncthreads();
  for(int i=tid;i<NN*NN;i+=256){ int n=i/NN,m=i%NN;
    float a=0;
    for(int t=0;t<TT;t++) a+=lhs[n*TT+t]*rhs[t*NN+m];
    P[i]=sigm(a+sa_bs[i]);
  }
  for(int i=tid;i<TT*TT;i+=256){ int t=i/TT,u=i%TT;
    float a=0;
    for(int n=0;n<NN;n++) a+=lhsT[t*NN+n]*rhsT[n*TT+u];
    PT[i]=sigm(a+ta_be[i]);
  }
  __syncthreads();
  for(int i=tid;i<NN*NN;i+=256){ int n=i/NN,k=i%NN;
    float a=0;
    for(int m=0;m<NN;m++) a+=sa_Vs[n*NN+m]*P[m*NN+k];
    S[i]=a;
  }
  for(int i=tid;i<TT*TT;i+=256){ int t=i/TT,v=i%TT;
    float a=0;
    for(int u=0;u<TT;u++) a+=ta_Ve[t*TT+u]*PT[u*TT+v];
    E[i]=a;
  }
  __syncthreads();
  if(tid<NN){ int k=tid;
    float mx=-1e30f;
    for(int n=0;n<NN;n++) mx=fmaxf(mx,S[n*NN+k]);
    float sm=0;
    for(int n=0;n<NN;n++) sm+=__expf(S[n*NN+k]-mx);
    for(int n=0;n<NN;n++){
      float v=__expf(S[n*NN+k]-mx)/sm;
      SA_pre[b*576+n*NN+k]=sigm(v);
    }
  }
  if(tid>=32 && tid<32+TT){ int v=tid-32;
    float mx=-1e30f;
    for(int t=0;t<TT;t++) mx=fmaxf(mx,E[t*TT+v]);
    float sm=0;
    for(int t=0;t<TT;t++) sm+=__expf(E[t*TT+v]-mx);
    for(int t=0;t<TT;t++){
      float e=__expf(E[t*TT+v]-mx)/sm;
      TA_pre[b*144+t*TT+v]=sigm(e);
    }
  }
}

// ---------- F2a: graph per (b,n) (0..767) + conv cg[8,16) (768..1002) + sa2 transpose (1003..1042) ----------
__global__ void __launch_bounds__(256) k_f2a(const float* __restrict__ X,
  const float* __restrict__ cheb, const float* __restrict__ SA_pre,
  const float* __restrict__ TA_pre, const float* __restrict__ theta,
  const float* __restrict__ cheb_bias, const float* __restrict__ ln_g,
  const float* __restrict__ ln_b, float* __restrict__ xres,
  float* __restrict__ out_sa,
  const float* __restrict__ W, unsigned short* __restrict__ Wp,
  const float* __restrict__ sa2_w, float* __restrict__ sa2_wT){
  __shared__ __align__(16) float smf[4352];
  int tid=threadIdx.x;
  if(blockIdx.x>=1003){
    int cb=blockIdx.x-1003;
    for(int idx=cb*256+tid; idx<DIN*DIN; idx+=40*256){
      int i=idx/DIN, j=idx-i*DIN;
      sa2_wT[idx]=sa2_w[(long)j*DIN+i];
    }
    return;
  }
  if(blockIdx.x>=768){
    conv_slab(W,Wp,blockIdx.x-768,8,16,tid,256,(unsigned short*)smf);
    return;
  }
  int b=blockIdx.x/NN, n=blockIdx.x%NN;
  float* lin=smf;          // 864
  float* tal=smf+864;      // 144
  float* sal=smf+1008;     // 24
  float* rg =smf+1032;     // 108
  float* xc =smf+1140;     // 144
  for(int i=tid;i<864;i+=256) lin[i]=X[b*864+i];
  if(tid<NN){ int m=tid; int mn=m*NN+n;
    float mx=-1e30f;
    for(int bb=0;bb<BSZ;bb++) mx=fmaxf(mx,SA_pre[bb*576+mn]);
    float sm=0;
    for(int bb=0;bb<BSZ;bb++) sm+=__expf(SA_pre[bb*576+mn]-mx);
    float v=__expf(SA_pre[b*576+mn]-mx)/sm;
    sal[m]=v;
    out_sa[b*576+mn]=v;
  }
  for(int i=tid;i<144;i+=256){
    float mx=-1e30f;
    for(int bb=0;bb<BSZ;bb++) mx=fmaxf(mx,TA_pre[bb*144+i]);
    float sm=0;
    for(int bb=0;bb<BSZ;bb++) sm+=__expf(TA_pre[bb*144+i]-mx);
    tal[i]=__expf(TA_pre[b*144+i]-mx)/sm;
  }
  __syncthreads();
  if(tid<108){
    int k=tid/36, f=(tid/12)%3, t=tid%12;
    float a=0;
    for(int m=0;m<NN;m++)
      a += (cheb[(k*NN+m)*NN+n]*sal[m])*lin[m*36+f*TT+t];
    rg[tid]=a;
  }
  __syncthreads();
  if(tid<144){
    int o=tid/12, t=tid%12;
    float a=cheb_bias[o];
    #pragma unroll
    for(int k=0;k<KK;k++)
      #pragma unroll
      for(int f=0;f<FF;f++)
        a += rg[k*36+f*12+t]*theta[(k*FF+f)*COUT+o];
    xc[tid]=fmaxf(a,0.f);
  }
  __syncthreads();
  if(tid<COUT){
    int o=tid;
    float mu=0;
    for(int t=0;t<TT;t++) mu+=xc[o*TT+t];
    mu*=(1.f/12.f);
    float var=0;
    for(int t=0;t<TT;t++){ float d=xc[o*TT+t]-mu; var+=d*d; }
    var*=(1.f/12.f);
    float inv=rsqrtf(var+1e-5f);
    for(int t=0;t<TT;t++) xc[o*TT+t]=(xc[o*TT+t]-mu)*inv*ln_g[t]+ln_b[t];
  }
  __syncthreads();
  if(tid<144){
    int o=tid/12, v=tid%12;
    float a=0;
    for(int t=0;t<TT;t++) a+=xc[o*TT+t]*tal[t*TT+v];
    xres[((long)b*DIN + n*COUT+o)*TT + v]=a;
  }
}

// ---------- F2b: x_in = xres @ liw^T + lib  (x_pre rows computed inline from X) ----------
__global__ void __launch_bounds__(256) k_f2b(const float* __restrict__ xres,
    const float* __restrict__ X, const float* __restrict__ liw,
    const float* __restrict__ lib, float* __restrict__ x_in){
  int id=blockIdx.x*256+threadIdx.x;
  if(id>=BSZ*DIN*TT) return;
  int t=id%TT, i=(id/TT)%DIN, b=id/(DIN*TT);
  float a=lib[t];
  if(i<288){
    const float* xr=xres+((long)b*DIN+i)*TT;
    #pragma unroll
    for(int u=0;u<TT;u++) a+=xr[u]*liw[t*TT+u];
  } else if(i<312){
    int r=i-288;
    #pragma unroll
    for(int u=0;u<TT;u++) a+=X[b*864+r*36+u*3+0]*liw[t*TT+u];
  } else {
    #pragma unroll
    for(int u=0;u<TT;u++) a+=X[b*864+u*3+1]*liw[t*TT+u];
  }
  x_in[id]=a;
}

// ---------- F3: alpha w/ transposed weights (0..383) + conv cg[16,23) ----------
__global__ void __launch_bounds__(512) k_f3(const float* __restrict__ x_in,
    const float* __restrict__ sa2_wT, const float* __restrict__ sa2_b,
    unsigned short* __restrict__ xi_b,
    const float* __restrict__ W, unsigned short* __restrict__ Wp){
  __shared__ __align__(16) float smf[4352];
  int tid=threadIdx.x;
  if(blockIdx.x>=384){
    conv_slab(W,Wp,blockIdx.x-384,16,23,tid,512,(unsigned short*)smf);
    return;
  }
  int blk=blockIdx.x; int t=blk>>5, b=blk&31;
  float* xt=smf;            // 313
  float* red=smf+320;       // 512
  if(tid<DIN) xt[tid]=x_in[((long)b*DIN+tid)*TT+t];
  __syncthreads();
  float z=-1e30f, e=0.f;
  if(tid<DIN){
    float a=sa2_b[tid];
    for(int i=0;i<DIN;i++) a+=xt[i]*sa2_wT[(long)i*DIN+tid];
    z=sigm(a);
  }
  red[tid]=z; __syncthreads();
  for(int off=256;off>0;off>>=1){ if(tid<off) red[tid]=fmaxf(red[tid],red[tid+off]); __syncthreads(); }
  float mx=red[0]; __syncthreads();
  e=(tid<DIN)?__expf(z-mx):0.f;
  red[tid]=e; __syncthreads();
  for(int off=256;off>0;off>>=1){ if(tid<off) red[tid]+=red[tid+off]; __syncthreads(); }
  float sm=red[0];
  if(tid<KPI){
    unsigned short v=0;
    if(tid<DIN){
      float alpha=e/sm;
      v=f2bf(xt[tid]*alpha+xt[tid]);
    }
    xi_b[(long)blk*KPI+tid]=v;
  }
}

// ---------- F4: gx w/ packed W_ih (0..117) + conv cg[23,30) + convh ----------
__global__ void __launch_bounds__(256) k_f4(const unsigned short* __restrict__ xi,
   const unsigned short* __restrict__ Wip, const float* __restrict__ b_ih,
   const float* __restrict__ b_hh, float* __restrict__ Gx,
   const float* __restrict__ W, unsigned short* __restrict__ Wp,
   const float* __restrict__ h0f, unsigned short* __restrict__ hb0,
   unsigned short* __restrict__ hb1){
  __shared__ __align__(16) float smf[4352];
  int tid=threadIdx.x;
  if(blockIdx.x>=118){
    int cb_=blockIdx.x-118;
    conv_slab(W,Wp,cb_,23,30,tid,256,(unsigned short*)smf);
    const int g4=KP>>2;
    for(int i=cb_*256+tid; i<BSZ*g4; i+=NB*256){
      int gq=i%g4, r=i/g4;
      int k=gq*4;
      float vv[4];
      if(k+3<HID){
        float4 x=*(const float4*)(h0f+(long)r*HID+k);
        vv[0]=x.x; vv[1]=x.y; vv[2]=x.z; vv[3]=x.w;
      } else {
        #pragma unroll
        for(int q=0;q<4;q++){ int kk=k+q; vv[q]=(kk<HID)? h0f[(long)r*HID+kk] : 0.f; }
      }
      ushort4 o;
      o.x=f2bf(vv[0]); o.y=f2bf(vv[1]); o.z=f2bf(vv[2]); o.w=f2bf(vv[3]);
      *(ushort4*)(hb0+(long)r*KP+k)=o;
      *(ushort4*)(hb1+(long)r*KP+k)=o;
    }
    return;
  }
  int w=tid>>6, lane=tid&63;
  int jt=blockIdx.x*4+w;
  if(jt>=NTILES) return;
  int j0=jt*32;
  int lj=lane&15, lk=lane>>4;
  const unsigned short* wslab = Wip + (long)jt*10240;
  short8 bfr[10][2];
  #pragma unroll
  for(int ks=0;ks<10;ks++)
    #pragma unroll
    for(int jh=0;jh<2;jh++)
      bfr[ks][jh]=*(const short8*)(wslab + ((ks*2+jh)<<9) + (lane<<3));
  for(int t=0;t<TT;t++){
    f32x4 acc[2][2]={};
    #pragma unroll
    for(int ks=0;ks<10;ks++){
      #pragma unroll
      for(int mh=0;mh<2;mh++){
        short8 a=*(const short8*)(xi + ((long)(t*32+mh*16+lj))*KPI + ks*32 + lk*8);
        acc[mh][0]=mfma16(a,bfr[ks][0],acc[mh][0]);
        acc[mh][1]=mfma16(a,bfr[ks][1],acc[mh][1]);
      }
    }
    #pragma unroll
    for(int mh=0;mh<2;mh++)
      #pragma unroll
      for(int jh=0;jh<2;jh++){
        int j=j0+jh*16+lj;
        if(j<H4){
          float bias=b_ih[j]+b_hh[j];
          #pragma unroll
          for(int r=0;r<4;r++){
            int bb=mh*16+lk*4+r;     // C/D: col=lane&15, row=(lane>>4)*4+r  (m89-verified)
            Gx[((long)t*32+bb)*H4+j]=acc[mh][jh][r]+bias;
          }
        }
      }
  }
}

// ---------- fused LSTM step (bf16, PACKED W slabs: contiguous 1KB loads) ----------
__global__ void __launch_bounds__(512) k_step(const unsigned short* __restrict__ hb_r,
    unsigned short* __restrict__ hb_w, const unsigned short* __restrict__ Wp,
    const float* __restrict__ Gx, const float* __restrict__ c0,
    float* __restrict__ c, float* __restrict__ hs, int t){
  const int tid=threadIdx.x;
  const int w=tid>>6, lane=tid&63;
  const int j0=blockIdx.x*16;
  const int lj=lane&15, lk=lane>>4;
  const int s0=(118*w)>>3, s1=(118*(w+1))>>3;
  const unsigned short* slab = Wp + (long)blockIdx.x*64*KP;
  f32x4 acc[4][2]={};
  #pragma unroll 2
  for(int ks=s0;ks<s1;ks++){
    int kofs=ks*32+lk*8;
    short8 a0=*(const short8*)(hb_r + (long)lj*KP + kofs);
    short8 a1=*(const short8*)(hb_r + (long)(16+lj)*KP + kofs);
    const unsigned short* pk = slab + ((long)ks<<11);
    #pragma unroll
    for(int g=0;g<4;g++){
      short8 bv=*(const short8*)(pk + (g<<9) + (lane<<3));
      acc[g][0]=mfma16(a0,bv,acc[g][0]);
      acc[g][1]=mfma16(a1,bv,acc[g][1]);
    }
  }
  __shared__ float red[8][4][512];
  #pragma unroll
  for(int g=0;g<4;g++)
    #pragma unroll
    for(int mh=0;mh<2;mh++)
      #pragma unroll
      for(int r=0;r<4;r++)
        red[w][g][(mh*16+lk*4+r)*16+lj]=acc[g][mh][r];
  __syncthreads();
  if(tid<512){
    int p=tid;
    int bb=p>>4, jl=p&15; int j=j0+jl;
    if(j<HID){
      long gxo=((long)t*BSZ+bb)*H4 + j;
      float si=0,sf=0,sg=0,so=0;
      #pragma unroll
      for(int ww=0;ww<8;ww++){
        si+=red[ww][0][p]; sf+=red[ww][1][p];
        sg+=red[ww][2][p]; so+=red[ww][3][p];
      }
      si+=Gx[gxo]; sf+=Gx[gxo+HID]; sg+=Gx[gxo+2*HID]; so+=Gx[gxo+3*HID];
      float gi=sigm(si), gf=sigm(sf), gg=tanhf(sg), go=sigm(so);
      int idx=bb*HID+j;
      float cin=(t==0)?c0[idx]:c[idx];
      float c2=gf*cin+gi*gg;
      float h2=go*tanhf(c2);
      c[idx]=c2;
      hs[(long)t*BSZ*HID+idx]=h2;
      hb_w[(long)bb*KP+j]=f2bf(h2);
    }
  }
}

// ---------- fused tail: beta softmax + weighted output ----------
__global__ void k_tail(const float* __restrict__ hs, const float* __restrict__ ta2_w,
   const float* __restrict__ ta2_b, const float* __restrict__ x_in,
   const float* __restrict__ out_w, const float* __restrict__ out_b,
   float* __restrict__ out0){
  int b=blockIdx.x, tid=threadIdx.x;
  float p[12]={0,0,0,0,0,0,0,0,0,0,0,0};
  for(int idx=tid; idx<TT*HID; idx+=256){
    int t=idx/HID, j=idx-t*HID;
    float v=hs[((long)t*BSZ+b)*HID+j];
    #pragma unroll
    for(int q=0;q<12;q++) p[q]+=v*ta2_w[(long)q*TT*HID+idx];
  }
  __shared__ float red[256];
  __shared__ float bt[12];
  float z[12];
  #pragma unroll
  for(int q=0;q<12;q++){
    __syncthreads();
    red[tid]=p[q]; __syncthreads();
    for(int off=128;off>0;off>>=1){ if(tid<off) red[tid]+=red[tid+off]; __syncthreads(); }
    z[q]=red[0];
  }
  if(tid==0){
    float mx=-1e30f;
    #pragma unroll
    for(int q=0;q<12;q++){ z[q]=fmaxf(z[q]+ta2_b[q],0.f); mx=fmaxf(mx,z[q]); }
    float sm=0;
    #pragma unroll
    for(int q=0;q<12;q++){ z[q]=__expf(z[q]-mx); sm+=z[q]; }
    #pragma unroll
    for(int q=0;q<12;q++) bt[q]=z[q]/sm;
  }
  __syncthreads();
  float acc=0;
  for(int j=tid;j<HID;j+=256){
    float ov=0;
    #pragma unroll
    for(int t=0;t<TT;t++) ov+=hs[((long)t*BSZ+b)*HID+j]*bt[t];
    ov+=x_in[(long)b*HID+j];
    acc+=fmaxf(ov,0.f)*out_w[j];
  }
  __syncthreads();
  red[tid]=acc; __syncthreads();
  for(int off=128;off>0;off>>=1){ if(tid<off) red[tid]+=red[tid+off]; __syncthreads(); }
  if(tid==0) out0[b]=red[0]+out_b[0];
}

extern "C" void kernel_launch(void* const* d_in, const int* in_sizes, int n_in,
                              void* d_out, int out_size, void* d_ws, size_t ws_size,
                              hipStream_t stream){
  (void)in_sizes; (void)n_in; (void)out_size; (void)ws_size;
  const float* X     =(const float*)d_in[0];
  const float* cheb  =(const float*)d_in[1];
  const float* sa_W1 =(const float*)d_in[2];
  const float* sa_W2 =(const float*)d_in[3];
  const float* sa_W3 =(const float*)d_in[4];
  const float* sa_bs =(const float*)d_in[5];
  const float* sa_Vs =(const float*)d_in[6];
  const float* ta_U1 =(const float*)d_in[7];
  const float* ta_U2 =(const float*)d_in[8];
  const float* ta_U3 =(const float*)d_in[9];
  const float* ta_be =(const float*)d_in[10];
  const float* ta_Ve =(const float*)d_in[11];
  const float* theta =(const float*)d_in[12];
  const float* cb    =(const float*)d_in[13];
  const float* ln_g  =(const float*)d_in[14];
  const float* ln_b  =(const float*)d_in[15];
  const float* liw   =(const float*)d_in[16];
  const float* lib   =(const float*)d_in[17];
  const float* sa2_w =(const float*)d_in[18];
  const float* sa2_b =(const float*)d_in[19];
  const float* W_ih  =(const float*)d_in[20];
  const float* W_hh  =(const float*)d_in[21];
  const float* b_ih  =(const float*)d_in[22];
  const float* b_hh  =(const float*)d_in[23];
  const float* ta2_w =(const float*)d_in[24];
  const float* ta2_b =(const float*)d_in[25];
  const float* out_w =(const float*)d_in[26];
  const float* out_b =(const float*)d_in[27];
  const float* h0    =(const float*)d_in[28];
  const float* c0    =(const float*)d_in[29];

  char* w=(char*)d_ws;
  unsigned short* Wp =(unsigned short*)(w);                   // 113,582,080
  float* Gx   =(float*)(w+113582080);                         // 23,076,864 -> 136,658,944
  float* hs   =(float*)(w+136658944);                         //  5,769,216 -> 142,428,160
  unsigned short* hb0=(unsigned short*)(w+142428160);         //    241,664 -> 142,669,824
  unsigned short* hb1=(unsigned short*)(w+142669824);         //    241,664 -> 142,911,488
  float* c    =(float*)(w+142911488);                         //    480,768 -> 143,392,256
  float* x_in =(float*)(w+143392256);                         //    480,768 -> 143,873,024
  unsigned short* xi_b=(unsigned short*)(w+143873024);        //    245,760 -> 144,118,784
  float* SA   =(float*)(w+144118784);                         //     73,728 -> 144,192,512
  float* TA   =(float*)(w+144192512);                         //     18,432 -> 144,210,944
  unsigned short* Wip=(unsigned short*)(w+144211968);         //  9,625,600 -> 153,837,568
  float* sa2T =(float*)(w+153837568);                         //    391,876 -> 154,229,444
  float* xres =(float*)(w+154229504);                         //    480,768 -> 154,710,272
  float* out_f=(float*)d_out;                                 // [0..31]=out, [32..]=s_a

  k_f1<<<385,256,0,stream>>>(X,sa_W1,sa_W2,sa_W3,sa_bs,sa_Vs,ta_U1,ta_U2,ta_U3,ta_be,ta_Ve,
                             SA,TA,W_hh,Wp,W_ih,Wip);
  k_f2a<<<1043,256,0,stream>>>(X,cheb,SA,TA,theta,cb,ln_g,ln_b,xres,out_f+32,W_hh,Wp,
                               sa2_w,sa2T);
  k_f2b<<<470,256,0,stream>>>(xres,X,liw,lib,x_in);
  k_f3<<<384+NB,512,0,stream>>>(x_in,sa2T,sa2_b,xi_b,W_hh,Wp);
  k_f4<<<118+NB,256,0,stream>>>(xi_b,Wip,b_ih,b_hh,Gx,W_hh,Wp,h0,hb0,hb1);
  unsigned short* hb[2]={hb0,hb1};
  for(int t=0;t<TT;t++)
    k_step<<<NB,512,0,stream>>>(hb[t&1],hb[(t+1)&1],Wp,Gx,c0,c,hs,t);
  k_tail<<<32,256,0,stream>>>(hs,ta2_w,ta2_b,x_in,out_w,out_b,out_f);
}

// Round 18
// 467.087 us; speedup vs baseline: 1.2075x; 1.2075x over previous
//
#include <hip/hip_runtime.h>

#define BSZ 32
#define NN 24
#define TT 12
#define FF 3
#define KK 3
#define COUT 12
#define DIN 313          // N*COUT + N + 1
#define HID 3756         // DIN*T
#define H4 15024         // 4*HID
#define KP 3776          // HID padded to 118*32
#define KPI 320          // DIN padded to 10*32
#define NTILES 470       // ceil(15024/32)
#define NB 235           // j-tiles for fused step
#define NCH 30           // K chunk-groups of 4 ks

using short8 = __attribute__((ext_vector_type(8))) short;
using f32x4  = __attribute__((ext_vector_type(4))) float;

__device__ inline unsigned short f2bf(float f){
  union{float f; unsigned u;} v; v.f=f;
  unsigned u=v.u;
  return (unsigned short)((u + 0x7FFFu + ((u>>16)&1u))>>16);
}
__device__ inline f32x4 mfma16(short8 a, short8 b, f32x4 c){
  return __builtin_amdgcn_mfma_f32_16x16x32_bf16(a,b,c,0,0,0);
}
__device__ inline float sigm(float x){ return 1.f/(1.f+expf(-x)); }

// ---------- pack W_hh chunk-groups [cg0,cg1) for slab bi (LDS transpose) ----------
__device__ void conv_slab(const float* __restrict__ W, unsigned short* __restrict__ Wp,
    int bi, int cg0, int cg1, int tid, int nthr, unsigned short* lds){
  for(int cg=cg0; cg<cg1; cg++){
    int ks0=cg*4;
    int nks=min(4,118-ks0);
    int nf4=nks*8;
    for(int q=tid;q<64*nf4;q+=nthr){
      int r=q/nf4, f4=q-r*nf4;
      int g=r>>4, lj=r&15;
      int jj=bi*16+lj; if(jj>=HID) jj=HID-1;
      const float* src=W+(long)(g*HID+jj)*HID;
      int k=ks0*32+f4*4;
      ushort4 o;
      if(k+3<HID){
        float4 v=*(const float4*)(src+k);
        o.x=f2bf(v.x); o.y=f2bf(v.y); o.z=f2bf(v.z); o.w=f2bf(v.w);
      } else {
        float vv[4];
        #pragma unroll
        for(int t2=0;t2<4;t2++){ int kk=k+t2; vv[t2]=(kk<HID)?src[kk]:0.f; }
        o.x=f2bf(vv[0]); o.y=f2bf(vv[1]); o.z=f2bf(vv[2]); o.w=f2bf(vv[3]);
      }
      *(ushort4*)(&lds[r*136+f4*4])=o;
    }
    __syncthreads();
    for(int idx=tid; idx<nks*4*64; idx+=nthr){
      int l=idx&63, g=(idx>>6)&3, kl=idx>>8;
      int lj=l&15, lk=l>>4;
      short8 v=*(short8*)(&lds[(g*16+lj)*136 + kl*32 + lk*8]);
      *(short8*)(Wp + (((long)(bi*118+ks0+kl)*4+g)*64 + l)*8) = v;
    }
    __syncthreads();
  }
}

// ---------- pack W_ih slab jt into per-wave-contiguous bf16 ----------
__device__ void pack_ih(const float* __restrict__ Wih, unsigned short* __restrict__ Wip,
    int jt, int tid, int nthr, unsigned short* lds /*32*328*/){
  int j0=jt*32;
  for(int q=tid;q<32*80;q+=nthr){
    int r=q/80, f4=q-r*80;
    int j=j0+r;
    int k=f4*4;
    ushort4 o;
    if(j<H4){
      const float* src=Wih+(long)j*DIN;
      float vv[4];
      #pragma unroll
      for(int t2=0;t2<4;t2++){ int kk=k+t2; vv[t2]=(kk<DIN)?src[kk]:0.f; }
      o.x=f2bf(vv[0]); o.y=f2bf(vv[1]); o.z=f2bf(vv[2]); o.w=f2bf(vv[3]);
    } else { o.x=0;o.y=0;o.z=0;o.w=0; }
    *(ushort4*)(&lds[r*328+k])=o;
  }
  __syncthreads();
  for(int u=tid;u<1280;u+=nthr){
    int l=u&63, jh=(u>>6)&1, ks=u>>7;
    int lj=l&15, lk=l>>4;
    short8 v=*(short8*)(&lds[(jh*16+lj)*328 + ks*32 + lk*8]);
    *(short8*)(Wip + (((long)(jt*10+ks)*2+jh)*512) + l*8)=v;
  }
  __syncthreads();
}

// ---------- F1: attn (0..31) + conv cg[0,8) (32..266) + packih (267..384) ----------
__global__ void __launch_bounds__(256) k_f1(const float* __restrict__ X,
   const float* __restrict__ sa_W1, const float* __restrict__ sa_W2,
   const float* __restrict__ sa_W3, const float* __restrict__ sa_bs,
   const float* __restrict__ sa_Vs, const float* __restrict__ ta_U1,
   const float* __restrict__ ta_U2, const float* __restrict__ ta_U3,
   const float* __restrict__ ta_be, const float* __restrict__ ta_Ve,
   float* __restrict__ SA_pre, float* __restrict__ TA_pre,
   const float* __restrict__ W, unsigned short* __restrict__ Wp,
   const float* __restrict__ Wih, unsigned short* __restrict__ Wip){
  __shared__ __align__(16) float smf[5248];
  int tid=threadIdx.x;
  if(blockIdx.x>=267){
    int cb=blockIdx.x-267;
    #pragma unroll
    for(int s=0;s<4;s++){
      int jt=cb*4+s;
      if(jt<NTILES) pack_ih(Wih,Wip,jt,tid,256,(unsigned short*)smf);
    }
    return;
  }
  if(blockIdx.x>=32){
    conv_slab(W,Wp,blockIdx.x-32,0,8,tid,256,(unsigned short*)smf);
    return;
  }
  int b=blockIdx.x;
  float* lin=smf;        float* lhs=smf+864;   float* rhs=smf+1152;
  float* P=smf+1440;     float* S=smf+2016;    float* lhsT=smf+2592;
  float* rhsT=smf+2880;  float* PT=smf+3168;   float* E=smf+3312;
  for(int i=tid;i<864;i+=256) lin[i]=X[b*864+i];
  __syncthreads();
  for(int i=tid;i<NN*TT;i+=256){ int n=i/TT, t=i%TT;
    float acc=0;
    #pragma unroll
    for(int f=0;f<FF;f++){
      float t1=0;
      for(int u=0;u<TT;u++) t1 += lin[n*36+u*3+f]*sa_W1[u];
      acc += t1*sa_W2[f*TT+t];
    }
    lhs[n*TT+t]=acc;
    float r=0;
    #pragma unroll
    for(int f=0;f<FF;f++) r += sa_W3[f]*lin[n*36+t*3+f];
    rhs[t*NN+n]=r;
  }
  for(int i=tid;i<TT*NN;i+=256){ int t=i/NN, n=i%NN;
    float acc=0;
    #pragma unroll
    for(int f=0;f<FF;f++){
      float t1=0;
      for(int m=0;m<NN;m++) t1 += lin[m*36+t*3+f]*ta_U1[m];
      acc += t1*ta_U2[f*NN+n];
    }
    lhsT[t*NN+n]=acc;
    float r=0;
    #pragma unroll
    for(int f=0;f<FF;f++) r += ta_U3[f]*lin[n*36+t*3+f];
    rhsT[n*TT+t]=r;
  }
  __syncthreads();
  for(int i=tid;i<NN*NN;i+=256){ int n=i/NN,m=i%NN;
    float a=0;
    for(int t=0;t<TT;t++) a+=lhs[n*TT+t]*rhs[t*NN+m];
    P[i]=sigm(a+sa_bs[i]);
  }
  for(int i=tid;i<TT*TT;i+=256){ int t=i/TT,u=i%TT;
    float a=0;
    for(int n=0;n<NN;n++) a+=lhsT[t*NN+n]*rhsT[n*TT+u];
    PT[i]=sigm(a+ta_be[i]);
  }
  __syncthreads();
  for(int i=tid;i<NN*NN;i+=256){ int n=i/NN,k=i%NN;
    float a=0;
    for(int m=0;m<NN;m++) a+=sa_Vs[n*NN+m]*P[m*NN+k];
    S[i]=a;
  }
  for(int i=tid;i<TT*TT;i+=256){ int t=i/TT,v=i%TT;
    float a=0;
    for(int u=0;u<TT;u++) a+=ta_Ve[t*TT+u]*PT[u*TT+v];
    E[i]=a;
  }
  __syncthreads();
  if(tid<NN){ int k=tid;
    float mx=-1e30f;
    for(int n=0;n<NN;n++) mx=fmaxf(mx,S[n*NN+k]);
    float sm=0;
    for(int n=0;n<NN;n++) sm+=__expf(S[n*NN+k]-mx);
    for(int n=0;n<NN;n++){
      float v=__expf(S[n*NN+k]-mx)/sm;
      SA_pre[b*576+n*NN+k]=sigm(v);
    }
  }
  if(tid>=32 && tid<32+TT){ int v=tid-32;
    float mx=-1e30f;
    for(int t=0;t<TT;t++) mx=fmaxf(mx,E[t*TT+v]);
    float sm=0;
    for(int t=0;t<TT;t++) sm+=__expf(E[t*TT+v]-mx);
    for(int t=0;t<TT;t++){
      float e=__expf(E[t*TT+v]-mx)/sm;
      TA_pre[b*144+t*TT+v]=sigm(e);
    }
  }
}

// ---------- F2: graph+bsoftmax (0..31) + conv cg[8,16) (32..266) + sa2 transpose (267..306) ----------
__global__ void __launch_bounds__(320) k_f2(const float* __restrict__ X,
  const float* __restrict__ cheb, const float* __restrict__ SA_pre,
  const float* __restrict__ TA_pre, const float* __restrict__ theta,
  const float* __restrict__ cheb_bias, const float* __restrict__ ln_g,
  const float* __restrict__ ln_b, const float* __restrict__ liw,
  const float* __restrict__ lib, float* __restrict__ x_in,
  float* __restrict__ out_sa,
  const float* __restrict__ W, unsigned short* __restrict__ Wp,
  const float* __restrict__ sa2_w, float* __restrict__ sa2_wT){
  __shared__ __align__(16) float smf[13116];
  int tid=threadIdx.x;
  if(blockIdx.x>=267){
    int cb=blockIdx.x-267;
    for(int idx=cb*320+tid; idx<DIN*DIN; idx+=40*320){
      int i=idx/DIN, j=idx-i*DIN;
      sa2_wT[idx]=sa2_w[(long)j*DIN+i];
    }
    return;
  }
  if(blockIdx.x>=32){
    conv_slab(W,Wp,blockIdx.x-32,8,16,tid,320,(unsigned short*)smf);
    return;
  }
  int b=blockIdx.x;
  float* lin =smf;          // 864
  float* A2  =smf+864;      // 1728
  float* rg  =smf+2592;     // 2592
  float* xc  =smf+5184;     // 3456
  float* xres=smf+8640;     // 3756
  float* tal =smf+12396;    // 144
  float* sa_l=smf+12540;    // 576
  for(int i=tid;i<864;i+=320) lin[i]=X[b*864+i];
  for(int i=tid;i<576;i+=320){
    float mx=-1e30f;
    for(int bb=0;bb<BSZ;bb++) mx=fmaxf(mx,SA_pre[bb*576+i]);
    float sm=0;
    for(int bb=0;bb<BSZ;bb++) sm+=__expf(SA_pre[bb*576+i]-mx);
    float v=__expf(SA_pre[b*576+i]-mx)/sm;
    sa_l[i]=v;
    out_sa[b*576+i]=v;
  }
  for(int i=tid;i<144;i+=320){
    float mx=-1e30f;
    for(int bb=0;bb<BSZ;bb++) mx=fmaxf(mx,TA_pre[bb*144+i]);
    float sm=0;
    for(int bb=0;bb<BSZ;bb++) sm+=__expf(TA_pre[bb*144+i]-mx);
    tal[i]=__expf(TA_pre[b*144+i]-mx)/sm;
  }
  __syncthreads();
  for(int i=tid;i<KK*NN*NN;i+=320){ int mn=i%576; A2[i]=cheb[i]*sa_l[mn]; }
  __syncthreads();
  for(int i=tid;i<KK*NN*FF*TT;i+=320){
    int t=i%TT, f=(i/TT)%FF, n=(i/36)%NN, k=i/864;
    float a=0;
    for(int m=0;m<NN;m++) a+=A2[k*576+m*NN+n]*lin[m*36+f*TT+t];
    rg[i]=a;
  }
  __syncthreads();
  for(int i=tid;i<NN*COUT*TT;i+=320){
    int t=i%TT, o=(i/TT)%COUT, n=i/(COUT*TT);
    float a=cheb_bias[o];
    #pragma unroll
    for(int k=0;k<KK;k++)
      #pragma unroll
      for(int f=0;f<FF;f++)
        a += rg[((k*NN+n)*FF+f)*TT+t]*theta[(k*FF+f)*COUT+o];
    xc[i]=fmaxf(a,0.f);
  }
  __syncthreads();
  if(tid<NN*COUT){
    float mu=0;
    for(int t=0;t<TT;t++) mu+=xc[tid*TT+t];
    mu*=(1.f/12.f);
    float var=0;
    for(int t=0;t<TT;t++){ float d=xc[tid*TT+t]-mu; var+=d*d; }
    var*=(1.f/12.f);
    float inv=rsqrtf(var+1e-5f);
    for(int t=0;t<TT;t++) xc[tid*TT+t]=(xc[tid*TT+t]-mu)*inv*ln_g[t]+ln_b[t];
  }
  __syncthreads();
  for(int i=tid;i<NN*COUT;i+=320){
    for(int v=0;v<TT;v++){
      float a=0;
      for(int t=0;t<TT;t++) a+=xc[i*TT+t]*tal[t*TT+v];
      xres[i*TT+v]=a;
    }
  }
  for(int i=tid;i<25*TT;i+=320){
    int r=i/TT, t=i%TT;
    float v=(r<NN)? lin[r*36+t*3+0] : lin[t*3+1];
    xres[(288+r)*TT+t]=v;
  }
  __syncthreads();
  for(int i=tid;i<DIN;i+=320){
    for(int t=0;t<TT;t++){
      float a=lib[t];
      #pragma unroll
      for(int u=0;u<TT;u++) a+=xres[i*TT+u]*liw[t*TT+u];
      x_in[((long)b*DIN+i)*TT+t]=a;
    }
  }
}

// ---------- F3: alpha w/ transposed weights (0..383) + conv cg[16,23) ----------
__global__ void __launch_bounds__(512) k_f3(const float* __restrict__ x_in,
    const float* __restrict__ sa2_wT, const float* __restrict__ sa2_b,
    unsigned short* __restrict__ xi_b,
    const float* __restrict__ W, unsigned short* __restrict__ Wp){
  __shared__ __align__(16) float smf[4352];
  int tid=threadIdx.x;
  if(blockIdx.x>=384){
    conv_slab(W,Wp,blockIdx.x-384,16,23,tid,512,(unsigned short*)smf);
    return;
  }
  int blk=blockIdx.x; int t=blk>>5, b=blk&31;
  float* xt=smf;            // 313
  float* red=smf+320;       // 512
  if(tid<DIN) xt[tid]=x_in[((long)b*DIN+tid)*TT+t];
  __syncthreads();
  float z=-1e30f, e=0.f;
  if(tid<DIN){
    float a=sa2_b[tid];
    for(int i=0;i<DIN;i++) a+=xt[i]*sa2_wT[(long)i*DIN+tid];
    z=sigm(a);
  }
  red[tid]=z; __syncthreads();
  for(int off=256;off>0;off>>=1){ if(tid<off) red[tid]=fmaxf(red[tid],red[tid+off]); __syncthreads(); }
  float mx=red[0]; __syncthreads();
  e=(tid<DIN)?__expf(z-mx):0.f;
  red[tid]=e; __syncthreads();
  for(int off=256;off>0;off>>=1){ if(tid<off) red[tid]+=red[tid+off]; __syncthreads(); }
  float sm=red[0];
  if(tid<KPI){
    unsigned short v=0;
    if(tid<DIN){
      float alpha=e/sm;
      v=f2bf(xt[tid]*alpha+xt[tid]);
    }
    xi_b[(long)blk*KPI+tid]=v;
  }
}

// ---------- F4: gx w/ packed W_ih (0..117) + conv cg[23,30) + convh ----------
__global__ void __launch_bounds__(256) k_f4(const unsigned short* __restrict__ xi,
   const unsigned short* __restrict__ Wip, const float* __restrict__ b_ih,
   const float* __restrict__ b_hh, float* __restrict__ Gx,
   const float* __restrict__ W, unsigned short* __restrict__ Wp,
   const float* __restrict__ h0f, unsigned short* __restrict__ hb0,
   unsigned short* __restrict__ hb1){
  __shared__ __align__(16) float smf[4352];
  int tid=threadIdx.x;
  if(blockIdx.x>=118){
    int cb_=blockIdx.x-118;
    conv_slab(W,Wp,cb_,23,30,tid,256,(unsigned short*)smf);
    const int g4=KP>>2;
    for(int i=cb_*256+tid; i<BSZ*g4; i+=NB*256){
      int gq=i%g4, r=i/g4;
      int k=gq*4;
      float vv[4];
      if(k+3<HID){
        float4 x=*(const float4*)(h0f+(long)r*HID+k);
        vv[0]=x.x; vv[1]=x.y; vv[2]=x.z; vv[3]=x.w;
      } else {
        #pragma unroll
        for(int q=0;q<4;q++){ int kk=k+q; vv[q]=(kk<HID)? h0f[(long)r*HID+kk] : 0.f; }
      }
      ushort4 o;
      o.x=f2bf(vv[0]); o.y=f2bf(vv[1]); o.z=f2bf(vv[2]); o.w=f2bf(vv[3]);
      *(ushort4*)(hb0+(long)r*KP+k)=o;
      *(ushort4*)(hb1+(long)r*KP+k)=o;
    }
    return;
  }
  int w=tid>>6, lane=tid&63;
  int jt=blockIdx.x*4+w;
  if(jt>=NTILES) return;
  int j0=jt*32;
  int lj=lane&15, lk=lane>>4;
  const unsigned short* wslab = Wip + (long)jt*10240;
  short8 bfr[10][2];
  #pragma unroll
  for(int ks=0;ks<10;ks++)
    #pragma unroll
    for(int jh=0;jh<2;jh++)
      bfr[ks][jh]=*(const short8*)(wslab + ((ks*2+jh)<<9) + (lane<<3));
  for(int t=0;t<TT;t++){
    f32x4 acc[2][2]={};
    #pragma unroll
    for(int ks=0;ks<10;ks++){
      #pragma unroll
      for(int mh=0;mh<2;mh++){
        short8 a=*(const short8*)(xi + ((long)(t*32+mh*16+lj))*KPI + ks*32 + lk*8);
        acc[mh][0]=mfma16(a,bfr[ks][0],acc[mh][0]);
        acc[mh][1]=mfma16(a,bfr[ks][1],acc[mh][1]);
      }
    }
    #pragma unroll
    for(int mh=0;mh<2;mh++)
      #pragma unroll
      for(int jh=0;jh<2;jh++){
        int j=j0+jh*16+lj;
        if(j<H4){
          float bias=b_ih[j]+b_hh[j];
          #pragma unroll
          for(int r=0;r<4;r++){
            int bb=mh*16+lk*4+r;     // C/D: col=lane&15, row=(lane>>4)*4+r  (m89-verified)
            Gx[((long)t*32+bb)*H4+j]=acc[mh][jh][r]+bias;
          }
        }
      }
  }
}

// ---------- fused LSTM step (bf16, PACKED W slabs) ----------
__global__ void __launch_bounds__(512) k_step(const unsigned short* __restrict__ hb_r,
    unsigned short* __restrict__ hb_w, const unsigned short* __restrict__ Wp,
    const float* __restrict__ Gx, const float* __restrict__ c0,
    float* __restrict__ c, float* __restrict__ hs, int t){
  const int tid=threadIdx.x;
  const int w=tid>>6, lane=tid&63;
  const int j0=blockIdx.x*16;
  const int lj=lane&15, lk=lane>>4;
  const int s0=(118*w)>>3, s1=(118*(w+1))>>3;
  const unsigned short* slab = Wp + (long)blockIdx.x*64*KP;
  f32x4 acc[4][2]={};
  #pragma unroll 2
  for(int ks=s0;ks<s1;ks++){
    int kofs=ks*32+lk*8;
    short8 a0=*(const short8*)(hb_r + (long)lj*KP + kofs);
    short8 a1=*(const short8*)(hb_r + (long)(16+lj)*KP + kofs);
    const unsigned short* pk = slab + ((long)ks<<11);
    #pragma unroll
    for(int g=0;g<4;g++){
      short8 bv=*(const short8*)(pk + (g<<9) + (lane<<3));
      acc[g][0]=mfma16(a0,bv,acc[g][0]);
      acc[g][1]=mfma16(a1,bv,acc[g][1]);
    }
  }
  __shared__ float red[8][4][512];
  #pragma unroll
  for(int g=0;g<4;g++)
    #pragma unroll
    for(int mh=0;mh<2;mh++)
      #pragma unroll
      for(int r=0;r<4;r++)
        red[w][g][(mh*16+lk*4+r)*16+lj]=acc[g][mh][r];
  __syncthreads();
  if(tid<512){
    int p=tid;
    int bb=p>>4, jl=p&15; int j=j0+jl;
    if(j<HID){
      long gxo=((long)t*BSZ+bb)*H4 + j;
      float si=0,sf=0,sg=0,so=0;
      #pragma unroll
      for(int ww=0;ww<8;ww++){
        si+=red[ww][0][p]; sf+=red[ww][1][p];
        sg+=red[ww][2][p]; so+=red[ww][3][p];
      }
      si+=Gx[gxo]; sf+=Gx[gxo+HID]; sg+=Gx[gxo+2*HID]; so+=Gx[gxo+3*HID];
      float gi=sigm(si), gf=sigm(sf), gg=tanhf(sg), go=sigm(so);
      int idx=bb*HID+j;
      float cin=(t==0)?c0[idx]:c[idx];
      float c2=gf*cin+gi*gg;
      float h2=go*tanhf(c2);
      c[idx]=c2;
      hs[(long)t*BSZ*HID+idx]=h2;
      hb_w[(long)bb*KP+j]=f2bf(h2);
    }
  }
}

// ---------- T1: zq partials — grid (384, 4): (b,q) x K-chunk ----------
__global__ void __launch_bounds__(256) k_t1(const float* __restrict__ hs,
    const float* __restrict__ ta2_w, float* __restrict__ zpart){
  int bq=blockIdx.x, s=blockIdx.y, tid=threadIdx.x;
  int b=bq/12, q=bq-b*12;
  const int CH=11268;                          // 45072/4
  int i0=s*CH, i1=i0+CH;
  const float* wq=ta2_w+(long)q*45072;
  float acc=0;
  for(int idx=i0+tid; idx<i1; idx+=256){
    int t=idx/HID, j=idx-t*HID;
    acc+=hs[((long)t*BSZ+b)*HID+j]*wq[idx];
  }
  __shared__ float red[256];
  red[tid]=acc; __syncthreads();
  for(int off=128;off>0;off>>=1){ if(tid<off) red[tid]+=red[tid+off]; __syncthreads(); }
  if(tid==0) zpart[(bq<<2)+s]=red[0];
}

// ---------- T2: zq merge + relu + per-b softmax -> beta ----------
__global__ void __launch_bounds__(384) k_t2(const float* __restrict__ zpart,
    const float* __restrict__ ta2_b, float* __restrict__ beta){
  __shared__ float zz[384];
  int tid=threadIdx.x;
  int b=tid/12, q=tid-b*12;
  float z=zpart[(tid<<2)]+zpart[(tid<<2)+1]+zpart[(tid<<2)+2]+zpart[(tid<<2)+3]+ta2_b[q];
  zz[tid]=fmaxf(z,0.f);
  __syncthreads();
  if(q==0){
    float mx=-1e30f;
    #pragma unroll
    for(int k=0;k<12;k++) mx=fmaxf(mx,zz[b*12+k]);
    float sm=0;
    float e[12];
    #pragma unroll
    for(int k=0;k<12;k++){ e[k]=__expf(zz[b*12+k]-mx); sm+=e[k]; }
    #pragma unroll
    for(int k=0;k<12;k++) beta[b*12+k]=e[k]/sm;
  }
}

// ---------- T3: ov partials — grid (32*8): (b, j-chunk) ----------
__global__ void __launch_bounds__(256) k_t3(const float* __restrict__ hs,
    const float* __restrict__ beta, const float* __restrict__ x_in,
    const float* __restrict__ out_w, float* __restrict__ opart){
  int blk=blockIdx.x, tid=threadIdx.x;
  int b=blk>>3, jc=blk&7;
  __shared__ float bt[12];
  if(tid<12) bt[tid]=beta[b*12+tid];
  __syncthreads();
  int j0=jc*470, j1=min(HID,j0+470);
  float acc=0;
  for(int j=j0+tid;j<j1;j+=256){
    float ov=0;
    #pragma unroll
    for(int t=0;t<TT;t++) ov+=hs[((long)t*BSZ+b)*HID+j]*bt[t];
    ov+=x_in[(long)b*HID+j];
    acc+=fmaxf(ov,0.f)*out_w[j];
  }
  __shared__ float red[256];
  red[tid]=acc; __syncthreads();
  for(int off=128;off>0;off>>=1){ if(tid<off) red[tid]+=red[tid+off]; __syncthreads(); }
  if(tid==0) opart[blk]=red[0];
}

// ---------- T4: final out ----------
__global__ void k_t4(const float* __restrict__ opart, const float* __restrict__ out_b,
    float* __restrict__ out0){
  int b=threadIdx.x;
  if(b>=BSZ) return;
  float a=out_b[0];
  #pragma unroll
  for(int jc=0;jc<8;jc++) a+=opart[(b<<3)+jc];
  out0[b]=a;
}

extern "C" void kernel_launch(void* const* d_in, const int* in_sizes, int n_in,
                              void* d_out, int out_size, void* d_ws, size_t ws_size,
                              hipStream_t stream){
  (void)in_sizes; (void)n_in; (void)out_size; (void)ws_size;
  const float* X     =(const float*)d_in[0];
  const float* cheb  =(const float*)d_in[1];
  const float* sa_W1 =(const float*)d_in[2];
  const float* sa_W2 =(const float*)d_in[3];
  const float* sa_W3 =(const float*)d_in[4];
  const float* sa_bs =(const float*)d_in[5];
  const float* sa_Vs =(const float*)d_in[6];
  const float* ta_U1 =(const float*)d_in[7];
  const float* ta_U2 =(const float*)d_in[8];
  const float* ta_U3 =(const float*)d_in[9];
  const float* ta_be =(const float*)d_in[10];
  const float* ta_Ve =(const float*)d_in[11];
  const float* theta =(const float*)d_in[12];
  const float* cb    =(const float*)d_in[13];
  const float* ln_g  =(const float*)d_in[14];
  const float* ln_b  =(const float*)d_in[15];
  const float* liw   =(const float*)d_in[16];
  const float* lib   =(const float*)d_in[17];
  const float* sa2_w =(const float*)d_in[18];
  const float* sa2_b =(const float*)d_in[19];
  const float* W_ih  =(const float*)d_in[20];
  const float* W_hh  =(const float*)d_in[21];
  const float* b_ih  =(const float*)d_in[22];
  const float* b_hh  =(const float*)d_in[23];
  const float* ta2_w =(const float*)d_in[24];
  const float* ta2_b =(const float*)d_in[25];
  const float* out_w =(const float*)d_in[26];
  const float* out_b =(const float*)d_in[27];
  const float* h0    =(const float*)d_in[28];
  const float* c0    =(const float*)d_in[29];

  char* w=(char*)d_ws;
  unsigned short* Wp =(unsigned short*)(w);                   // 113,582,080
  float* Gx   =(float*)(w+113582080);                         // 23,076,864 -> 136,658,944
  float* hs   =(float*)(w+136658944);                         //  5,769,216 -> 142,428,160
  unsigned short* hb0=(unsigned short*)(w+142428160);         //    241,664 -> 142,669,824
  unsigned short* hb1=(unsigned short*)(w+142669824);         //    241,664 -> 142,911,488
  float* c    =(float*)(w+142911488);                         //    480,768 -> 143,392,256
  float* x_in =(float*)(w+143392256);                         //    480,768 -> 143,873,024
  unsigned short* xi_b=(unsigned short*)(w+143873024);        //    245,760 -> 144,118,784
  float* SA   =(float*)(w+144118784);                         //     73,728 -> 144,192,512
  float* TA   =(float*)(w+144192512);                         //     18,432 -> 144,210,944
  unsigned short* Wip=(unsigned short*)(w+144211968);         //  9,625,600 -> 153,837,568
  float* sa2T =(float*)(w+153837568);                         //    391,876 -> 154,229,444
  float* zpart=(float*)(w+154229504);                         //      6,144 -> 154,235,648
  float* beta =(float*)(w+154235648);                         //      1,536 -> 154,237,184
  float* opart=(float*)(w+154237184);                         //      1,024 -> 154,238,208
  float* out_f=(float*)d_out;                                 // [0..31]=out, [32..]=s_a

  k_f1<<<385,256,0,stream>>>(X,sa_W1,sa_W2,sa_W3,sa_bs,sa_Vs,ta_U1,ta_U2,ta_U3,ta_be,ta_Ve,
                             SA,TA,W_hh,Wp,W_ih,Wip);
  k_f2<<<307,320,0,stream>>>(X,cheb,SA,TA,theta,cb,ln_g,ln_b,liw,lib,x_in,out_f+32,W_hh,Wp,
                             sa2_w,sa2T);
  k_f3<<<384+NB,512,0,stream>>>(x_in,sa2T,sa2_b,xi_b,W_hh,Wp);
  k_f4<<<118+NB,256,0,stream>>>(xi_b,Wip,b_ih,b_hh,Gx,W_hh,Wp,h0,hb0,hb1);
  unsigned short* hb[2]={hb0,hb1};
  for(int t=0;t<TT;t++)
    k_step<<<NB,512,0,stream>>>(hb[t&1],hb[(t+1)&1],Wp,Gx,c0,c,hs,t);
  k_t1<<<dim3(384,4),256,0,stream>>>(hs,ta2_w,zpart);
  k_t2<<<1,384,0,stream>>>(zpart,ta2_b,beta);
  k_t3<<<256,256,0,stream>>>(hs,beta,x_in,out_w,opart);
  k_t4<<<1,64,0,stream>>>(opart,out_b,out_f);
}